// Round 3
// baseline (212.216 us; speedup 1.0000x reference)
//
#include <hip/hip_runtime.h>
#include <math.h>

#define NI   32
#define NH   1024
#define NB   1024

// ws layout. g-axis (h2) degree-SORTED; h1-axis natural. W2/W1 stored as BF16.
//   fp32: b1s[1056] @0, b2s[1024] @1056, W3s[64][1024] @2080
//   W1B  (uint)  @67616 : W1B[k][su] = bf16(W1m[j=2k][su]) | bf16(W1m[2k+1][su])<<16
//   PB   (uint4) @84512 : panel dd, pair u2, sg-quad Q, halves r=0/1
#define OFF_B1S 0
#define OFF_B2S 1056
#define OFF_W3S 2080
#define OFF_W1B 67616            // float-index (4B units)
#define OFF_PB  84512            // float-index; PB block idx = (dd*17+u2)*256 + Q

__device__ __forceinline__ int base_of(int d) { return (d == 0) ? 0 : 33 * d + 1; }

__device__ __forceinline__ unsigned short f2bf(float f) {   // RNE bf16
    unsigned u = __float_as_uint(f);
    return (unsigned short)((u + 0x7FFFu + ((u >> 16) & 1u)) >> 16);
}
__device__ __forceinline__ float bflo(unsigned u) { return __uint_as_float(u << 16); }
__device__ __forceinline__ float bfhi(unsigned u) { return __uint_as_float(u & 0xFFFF0000u); }

// ---- prep (identical — untouched for clean attribution) ----
template <int CNT>
__device__ __forceinline__ void prep_w2_cls(int d, int oh0, const float* __restrict__ W2,
                                            unsigned short* __restrict__ pb16, int t,
                                            float (*tile)[65]) {
    const int bse = base_of(d);
#pragma unroll 1
    for (int e = t; e < CNT * 64; e += 256) {
        int k = e >> 6, c = e & 63;
        int og = d + 31 * k;
        tile[k][c] = W2[(size_t)og * NH + oh0 + c];
    }
    __syncthreads();
#pragma unroll 1
    for (int e = t; e < 64 * CNT; e += 256) {
        int oh_l = e / CNT;
        int k = e - oh_l * CNT;
        int oh = oh0 + oh_l;
        int dd = oh % 31, u = oh / 31;
        int sg = bse + k;
        float v = (d >= dd) ? tile[k][oh_l] : 0.0f;
        size_t a = (size_t)((dd * 17 + (u >> 1)) * 256 + (sg >> 2)) * 8
                 + (u & 1) * 4 + (sg & 3);
        pb16[a] = f2bf(v);
    }
}

template <int CNT>
__device__ __forceinline__ void prep_small_cls(int d, const float* __restrict__ W1,
        const float* __restrict__ b1, const float* __restrict__ b2,
        const float* __restrict__ W3, float* __restrict__ ws, int t) {
    const int bse = base_of(d);
    unsigned short* w1b16 = (unsigned short*)(ws + OFF_W1B);
#pragma unroll 1
    for (int e = t; e < 64 * CNT; e += 256) {
        int o = e / CNT, k = e - o * CNT;
        int og = d + 31 * k;
        float v = (((o & 31) - 1) >= d) ? W3[(size_t)o * NH + og] : 0.0f;
        ws[OFF_W3S + (size_t)o * NH + bse + k] = v;
    }
#pragma unroll 1
    for (int e = t; e < 32 * CNT; e += 256) {
        int j = e / CNT, k = e - j * CNT;
        int og = d + 31 * k;
        int su = bse + k;
        float v = (d >= j) ? W1[og * NI + j] : 0.0f;
        w1b16[(size_t)((j >> 1) * 1056 + su) * 2 + (j & 1)] = f2bf(v);
    }
    if (t < CNT) {
        int og = d + 31 * t;
        ws[OFF_B1S + bse + t] = b1[og];
        ws[OFF_B2S + bse + t] = b2[og];
    }
}

__global__ __launch_bounds__(256) void prep_all(const float* __restrict__ W1,
        const float* __restrict__ b1, const float* __restrict__ W2,
        const float* __restrict__ b2, const float* __restrict__ W3,
        float* __restrict__ ws) {
    __shared__ float tile[34][65];
    const int bid = blockIdx.x, t = threadIdx.x;
    unsigned short* pb16 = (unsigned short*)(ws + OFF_PB);
    if (bid < 496) {
        int d = bid >> 4, oh0 = (bid & 15) * 64;
        if (d == 0) prep_w2_cls<34>(0, oh0, W2, pb16, t, tile);
        else        prep_w2_cls<33>(d, oh0, W2, pb16, t, tile);
    } else {
        int d = bid - 496;
        if (d == 0) prep_small_cls<34>(0, W1, b1, b2, W3, ws, t);
        else        prep_small_cls<33>(d, W1, b1, b2, W3, ws, t);
    }
}

// one bf16 pair-load, SINGLE batch row; av = { a[2u2], a[2u2+1] } via 8B
// uniform-address LDS broadcast read.
__device__ __forceinline__ void consume_pair1(uint4 g, float2 av, float4& acc) {
    float f0 = bflo(g.x), f1 = bfhi(g.x), f2 = bflo(g.y), f3 = bfhi(g.y);
    float f4 = bflo(g.z), f5 = bfhi(g.z), f6 = bflo(g.w), f7 = bfhi(g.w);
    acc.x = fmaf(av.x, f0, acc.x); acc.y = fmaf(av.x, f1, acc.y);
    acc.z = fmaf(av.x, f2, acc.z); acc.w = fmaf(av.x, f3, acc.w);
    acc.x = fmaf(av.y, f4, acc.x); acc.y = fmaf(av.y, f5, acc.y);
    acc.z = fmaf(av.y, f6, acc.z); acc.w = fmaf(av.y, f7, acc.w);
}

// R16 (resubmit — R2 bench was an infra failure, not a kernel failure):
// block = 1 batch row x 4 slice-waves, grid 1024 (4 blocks/CU target).
// R15 forced __launch_bounds__(256,4) -> compiler capped VGPR at 64 and
// SPILLED (WRITE_SIZE 144KB -> 7.3MB of scratch traffic; dur 99->134us).
// Fix: relax to (256,2). The 1-row live set (~70-80 VGPR, cf. R14's 76 with
// MORE state) fits under the 128-reg threshold, so the HW still co-schedules
// 4 blocks/CU — occupancy gain WITHOUT spills.
// rot: co-resident set {b, b+256, b+512, b+768} covers all 4 rotations so
// heavy waves land on different SIMDs.
__global__ __launch_bounds__(256, 2) void made_scan(
        const float* __restrict__ inputs,
        const float* __restrict__ b3,
        const float* __restrict__ ws,
        float* __restrict__ out) {
    __shared__ float xsS[4][36];        // per-wave private x (pad 36)
    __shared__ float a1S[4][40];        // per-wave private a1 [unit]
    __shared__ float part[2][4][2];
    __shared__ float b3S[64];
    __shared__ float xinS[NI];

    const int lane = threadIdx.x & 63;
    const int w    = threadIdx.x >> 6;
    const int rot  = (blockIdx.x + (blockIdx.x >> 8)) & 3;
    const int q    = (w + rot) & 3;
    const int gb   = q * 256;
    const int row  = blockIdx.x;

    const float* b1s = ws + OFF_B1S;
    const float* b2s = ws + OFF_B2S;
    const float* W3s = ws + OFF_W3S;
    const unsigned* W1B = (const unsigned*)(ws + OFF_W1B);
    const uint4*    PB  = (const uint4*)(ws + OFF_PB);

    float4 acc = ((const float4*)(b2s + gb))[lane];
    float J = 0.f;

    if (w == 0) {
        b3S[lane] = b3[lane];
        if (lane < NI) xinS[lane] = inputs[row * NI + lane];
    }
    if (lane < 36) xsS[w][lane] = 0.f;
    __syncthreads();

    // step 0: W3 rows 0/32 fully masked -> p = (b3[0], b3[32])
    {
        float p00 = b3S[0], p01 = b3S[NI];
        float e20 = __expf(2.f * fminf(p01, 15.f));
        float ta  = (e20 - 1.f) / (e20 + 1.f);
        float x0  = fmaf(xinS[0], __expf(ta), p00);
        J -= ta;
        if (lane == 0) xsS[w][0] = x0;
    }

#pragma unroll 1
    for (int i = 1; i < NI; ++i) {
        const int dd   = i - 1;
        const int goff = base_of(dd);
        const int cnt  = (i == 1) ? 34 : 33;
        const bool doB = (gb + 256 > goff);
        const bool doC = (gb < 33 * i + 1);

        float4 wa = make_float4(0, 0, 0, 0), wb = make_float4(0, 0, 0, 0);
        if (doC) {
            wa = ((const float4*)(W3s + (size_t)i * NH + gb))[lane];
            wb = ((const float4*)(W3s + (size_t)(NI + i) * NH + gb))[lane];
        }

        if (doB) {
            const uint4* pbase = PB + (size_t)(dd * 17) * 256 + (gb >> 2) + lane;
            uint4 G1[9];
#pragma unroll
            for (int u2 = 0; u2 < 9; ++u2) G1[u2] = pbase[u2 * 256];
            __builtin_amdgcn_sched_barrier(0);

            // Phase A: 32 taps; x from private LDS (b128 broadcast), W1 bf16.
            // Taps j>=i have weight exactly 0 and xs[j]=0 -> exact.
            const int su = goff + lane;
            float bz = b1s[su];
            unsigned wk[16];
#pragma unroll
            for (int k = 0; k < 16; ++k) wk[k] = W1B[k * 1056 + su];
            float z0 = bz, z1 = 0, z2 = 0, z3 = 0;
#pragma unroll
            for (int j4 = 0; j4 < 8; ++j4) {
                float4 xq = *(const float4*)&xsS[w][4 * j4];
                float w0 = bflo(wk[2 * j4]),     w1 = bfhi(wk[2 * j4]);
                float w2 = bflo(wk[2 * j4 + 1]), w3 = bfhi(wk[2 * j4 + 1]);
                z0 = fmaf(xq.x, w0, z0);
                z1 = fmaf(xq.y, w1, z1);
                z2 = fmaf(xq.z, w2, z2);
                z3 = fmaf(xq.w, w3, z3);
            }
            const bool ok = lane < cnt;
            float a0 = ok ? fmaxf((z0 + z1) + (z2 + z3), 0.f) : 0.f;
            if (lane < 36) a1S[w][lane] = a0;   // publish to own-wave a1S
            __builtin_amdgcn_sched_barrier(0);

            uint4 G2[8];
#pragma unroll
            for (int u2 = 0; u2 < 8; ++u2) G2[u2] = pbase[(9 + u2) * 256];
            __builtin_amdgcn_sched_barrier(0);
#pragma unroll
            for (int u2 = 0; u2 < 9; ++u2)
                consume_pair1(G1[u2], *(const float2*)&a1S[w][2 * u2], acc);
            __builtin_amdgcn_sched_barrier(0);
#pragma unroll
            for (int u2 = 0; u2 < 8; ++u2)
                consume_pair1(G2[u2], *(const float2*)&a1S[w][18 + 2 * u2], acc);
        }

        // Phase C (fp32 W3; zeros beyond prefix keep it exact)
        float s00 = 0, s01 = 0;
        if (doC) {
            float hx = fmaxf(acc.x, 0.f), hy = fmaxf(acc.y, 0.f);
            float hz = fmaxf(acc.z, 0.f), hw = fmaxf(acc.w, 0.f);
            s00 = fmaf(wa.x, hx, fmaf(wa.y, hy, fmaf(wa.z, hz, wa.w * hw)));
            s01 = fmaf(wb.x, hx, fmaf(wb.y, hy, fmaf(wb.z, hz, wb.w * hw)));
#pragma unroll
            for (int m = 32; m >= 1; m >>= 1) {
                s00 += __shfl_xor(s00, m, 64);
                s01 += __shfl_xor(s01, m, 64);
            }
        }
        if (lane == 0)
            *((float2*)&part[i & 1][w][0]) = make_float2(s00, s01);
        __syncthreads();

        // combine — replicated in every wave; x published to own-wave xs only
        const float* pb = &part[i & 1][0][0];
        float4 q0 = ((const float4*)pb)[0], q1 = ((const float4*)pb)[1];
        float bi  = b3S[i];
        float bia = b3S[NI + i];
        float p00 = ((q0.x + q0.z) + (q1.x + q1.z)) + bi;
        float p01 = ((q0.y + q0.w) + (q1.y + q1.w)) + bia;
        float e20 = __expf(2.f * fminf(p01, 15.f));
        float ta0 = (e20 - 1.f) / (e20 + 1.f);
        float x0  = fmaf(xinS[i], __expf(ta0), p00);
        J -= ta0;
        if (lane == 0) xsS[w][i] = x0;
    }

    if (w == 0) {
        if (lane < NI) out[row * NI + lane] = xsS[0][lane];
        if (lane == 0) out[NB * NI + row] = J;
    }
}

extern "C" void kernel_launch(void* const* d_in, const int* in_sizes, int n_in,
                              void* d_out, int out_size, void* d_ws, size_t ws_size,
                              hipStream_t stream) {
    const float* inputs = (const float*)d_in[0];
    const float* W1     = (const float*)d_in[1];
    const float* b1     = (const float*)d_in[2];
    const float* W2     = (const float*)d_in[3];
    const float* b2     = (const float*)d_in[4];
    const float* W3     = (const float*)d_in[5];
    const float* b3     = (const float*)d_in[6];
    float* out = (float*)d_out;
    float* ws  = (float*)d_ws;

    prep_all<<<527, 256, 0, stream>>>(W1, b1, W2, b2, W3, ws);
    made_scan<<<NB, 256, 0, stream>>>(inputs, b3, ws, out);
}

// Round 4
// 183.427 us; speedup vs baseline: 1.1570x; 1.1570x over previous
//
#include <hip/hip_runtime.h>
#include <math.h>

#define NI   32
#define NH   1024
#define NB   1024

// ws layout. g-axis (h2) degree-SORTED; h1-axis natural. W2/W1 stored as BF16.
//   fp32: b1s[1056] @0, b2s[1024] @1056, W3s[64][1024] @2080
//   W1B  (uint)  @67616 : W1B[k][su] = bf16(W1m[j=2k][su]) | bf16(W1m[2k+1][su])<<16
//   PB   (uint4) @84512 : panel dd, pair u2, sg-quad Q, halves r=0/1
#define OFF_B1S 0
#define OFF_B2S 1056
#define OFF_W3S 2080
#define OFF_W1B 67616            // float-index (4B units)
#define OFF_PB  84512            // float-index; PB block idx = (dd*17+u2)*256 + Q

__device__ __forceinline__ int base_of(int d) { return (d == 0) ? 0 : 33 * d + 1; }

__device__ __forceinline__ unsigned short f2bf(float f) {   // RNE bf16
    unsigned u = __float_as_uint(f);
    return (unsigned short)((u + 0x7FFFu + ((u >> 16) & 1u)) >> 16);
}
__device__ __forceinline__ float bflo(unsigned u) { return __uint_as_float(u << 16); }
__device__ __forceinline__ float bfhi(unsigned u) { return __uint_as_float(u & 0xFFFF0000u); }

// ---- prep (identical — untouched for clean attribution) ----
template <int CNT>
__device__ __forceinline__ void prep_w2_cls(int d, int oh0, const float* __restrict__ W2,
                                            unsigned short* __restrict__ pb16, int t,
                                            float (*tile)[65]) {
    const int bse = base_of(d);
#pragma unroll 1
    for (int e = t; e < CNT * 64; e += 256) {
        int k = e >> 6, c = e & 63;
        int og = d + 31 * k;
        tile[k][c] = W2[(size_t)og * NH + oh0 + c];
    }
    __syncthreads();
#pragma unroll 1
    for (int e = t; e < 64 * CNT; e += 256) {
        int oh_l = e / CNT;
        int k = e - oh_l * CNT;
        int oh = oh0 + oh_l;
        int dd = oh % 31, u = oh / 31;
        int sg = bse + k;
        float v = (d >= dd) ? tile[k][oh_l] : 0.0f;
        size_t a = (size_t)((dd * 17 + (u >> 1)) * 256 + (sg >> 2)) * 8
                 + (u & 1) * 4 + (sg & 3);
        pb16[a] = f2bf(v);
    }
}

template <int CNT>
__device__ __forceinline__ void prep_small_cls(int d, const float* __restrict__ W1,
        const float* __restrict__ b1, const float* __restrict__ b2,
        const float* __restrict__ W3, float* __restrict__ ws, int t) {
    const int bse = base_of(d);
    unsigned short* w1b16 = (unsigned short*)(ws + OFF_W1B);
#pragma unroll 1
    for (int e = t; e < 64 * CNT; e += 256) {
        int o = e / CNT, k = e - o * CNT;
        int og = d + 31 * k;
        float v = (((o & 31) - 1) >= d) ? W3[(size_t)o * NH + og] : 0.0f;
        ws[OFF_W3S + (size_t)o * NH + bse + k] = v;
    }
#pragma unroll 1
    for (int e = t; e < 32 * CNT; e += 256) {
        int j = e / CNT, k = e - j * CNT;
        int og = d + 31 * k;
        int su = bse + k;
        float v = (d >= j) ? W1[og * NI + j] : 0.0f;
        w1b16[(size_t)((j >> 1) * 1056 + su) * 2 + (j & 1)] = f2bf(v);
    }
    if (t < CNT) {
        int og = d + 31 * t;
        ws[OFF_B1S + bse + t] = b1[og];
        ws[OFF_B2S + bse + t] = b2[og];
    }
}

__global__ __launch_bounds__(256) void prep_all(const float* __restrict__ W1,
        const float* __restrict__ b1, const float* __restrict__ W2,
        const float* __restrict__ b2, const float* __restrict__ W3,
        float* __restrict__ ws) {
    __shared__ float tile[34][65];
    const int bid = blockIdx.x, t = threadIdx.x;
    unsigned short* pb16 = (unsigned short*)(ws + OFF_PB);
    if (bid < 496) {
        int d = bid >> 4, oh0 = (bid & 15) * 64;
        if (d == 0) prep_w2_cls<34>(0, oh0, W2, pb16, t, tile);
        else        prep_w2_cls<33>(d, oh0, W2, pb16, t, tile);
    } else {
        int d = bid - 496;
        if (d == 0) prep_small_cls<34>(0, W1, b1, b2, W3, ws, t);
        else        prep_small_cls<33>(d, W1, b1, b2, W3, ws, t);
    }
}

// one bf16 pair-load, SINGLE batch row; av = { a[2u2], a[2u2+1] } via 8B
// uniform-address LDS broadcast read.
__device__ __forceinline__ void consume_pair1(uint4 g, float2 av, float4& acc) {
    float f0 = bflo(g.x), f1 = bfhi(g.x), f2 = bflo(g.y), f3 = bfhi(g.y);
    float f4 = bflo(g.z), f5 = bfhi(g.z), f6 = bflo(g.w), f7 = bfhi(g.w);
    acc.x = fmaf(av.x, f0, acc.x); acc.y = fmaf(av.x, f1, acc.y);
    acc.z = fmaf(av.x, f2, acc.z); acc.w = fmaf(av.x, f3, acc.w);
    acc.x = fmaf(av.y, f4, acc.x); acc.y = fmaf(av.y, f5, acc.y);
    acc.z = fmaf(av.y, f6, acc.z); acc.w = fmaf(av.y, f7, acc.w);
}

// R17: 1 row x 4 slice-waves, grid 1024, launch_bounds (256,4).
// Evidence so far: resident blocks/CU tracked the launch-bounds 2nd arg
// ((256,4)->3, (256,2)->2), NOT the VGPR count; and R15's spills came from
// my sched_barrier-pinned G1[9]/G2[8] staging forcing >=68 load-dest VGPRs
// live at once — impossible under the 64-reg (256,4) budget.
// Fix: KEEP (256,4); DELETE all sched_barriers and explicit G staging.
// Load+consume fused in one unrolled loop (compiler picks prefetch depth
// within the 64-reg budget — 3-4 resident blocks/CU now cover L2 latency),
// wk split 8+8, wa/wb deferred until after Phase A (in flight, not live).
// Estimated peak live ~56-62 VGPR -> genuine no-spill fit at 64.
__global__ __launch_bounds__(256, 4) void made_scan(
        const float* __restrict__ inputs,
        const float* __restrict__ b3,
        const float* __restrict__ ws,
        float* __restrict__ out) {
    __shared__ float xsS[4][36];        // per-wave private x (pad 36)
    __shared__ float a1S[4][40];        // per-wave private a1 [unit]
    __shared__ float part[2][4][2];
    __shared__ float b3S[64];
    __shared__ float xinS[NI];

    const int lane = threadIdx.x & 63;
    const int w    = threadIdx.x >> 6;
    const int rot  = (blockIdx.x + (blockIdx.x >> 8)) & 3;
    const int q    = (w + rot) & 3;
    const int gb   = q * 256;
    const int row  = blockIdx.x;

    const float* b1s = ws + OFF_B1S;
    const float* b2s = ws + OFF_B2S;
    const float* W3s = ws + OFF_W3S;
    const unsigned* W1B = (const unsigned*)(ws + OFF_W1B);
    const uint4*    PB  = (const uint4*)(ws + OFF_PB);

    float4 acc = ((const float4*)(b2s + gb))[lane];
    float J = 0.f;

    if (w == 0) {
        b3S[lane] = b3[lane];
        if (lane < NI) xinS[lane] = inputs[row * NI + lane];
    }
    if (lane < 36) xsS[w][lane] = 0.f;
    __syncthreads();

    // step 0: W3 rows 0/32 fully masked -> p = (b3[0], b3[32])
    {
        float p00 = b3S[0], p01 = b3S[NI];
        float e20 = __expf(2.f * fminf(p01, 15.f));
        float ta  = (e20 - 1.f) / (e20 + 1.f);
        float x0  = fmaf(xinS[0], __expf(ta), p00);
        J -= ta;
        if (lane == 0) xsS[w][0] = x0;
    }

#pragma unroll 1
    for (int i = 1; i < NI; ++i) {
        const int dd   = i - 1;
        const int goff = base_of(dd);
        const int cnt  = (i == 1) ? 34 : 33;
        const bool doB = (gb + 256 > goff);
        const bool doC = (gb < 33 * i + 1);

        if (doB) {
            // Phase A: 32 taps; x from private LDS (b128 broadcast), W1 bf16.
            // Taps j>=i have weight exactly 0 and xs[j]=0 -> exact.
            // wk split into two 8-reg halves to cut peak live registers.
            const int su = goff + lane;
            float bz = b1s[su];
            float z0 = bz, z1 = 0, z2 = 0, z3 = 0;
            {
                unsigned wkA[8];
#pragma unroll
                for (int k = 0; k < 8; ++k) wkA[k] = W1B[k * 1056 + su];
#pragma unroll
                for (int j4 = 0; j4 < 4; ++j4) {
                    float4 xq = *(const float4*)&xsS[w][4 * j4];
                    float w0 = bflo(wkA[2 * j4]),     w1 = bfhi(wkA[2 * j4]);
                    float w2 = bflo(wkA[2 * j4 + 1]), w3 = bfhi(wkA[2 * j4 + 1]);
                    z0 = fmaf(xq.x, w0, z0);
                    z1 = fmaf(xq.y, w1, z1);
                    z2 = fmaf(xq.z, w2, z2);
                    z3 = fmaf(xq.w, w3, z3);
                }
            }
            {
                unsigned wkB[8];
#pragma unroll
                for (int k = 0; k < 8; ++k) wkB[k] = W1B[(8 + k) * 1056 + su];
#pragma unroll
                for (int j4 = 0; j4 < 4; ++j4) {
                    float4 xq = *(const float4*)&xsS[w][16 + 4 * j4];
                    float w0 = bflo(wkB[2 * j4]),     w1 = bfhi(wkB[2 * j4]);
                    float w2 = bflo(wkB[2 * j4 + 1]), w3 = bfhi(wkB[2 * j4 + 1]);
                    z0 = fmaf(xq.x, w0, z0);
                    z1 = fmaf(xq.y, w1, z1);
                    z2 = fmaf(xq.z, w2, z2);
                    z3 = fmaf(xq.w, w3, z3);
                }
            }
            const bool ok = lane < cnt;
            float a0 = ok ? fmaxf((z0 + z1) + (z2 + z3), 0.f) : 0.f;
            if (lane < 36) a1S[w][lane] = a0;   // publish to own-wave a1S
        }

        // W3 rows for Phase C: issued here so they're in flight during consume
        float4 wa = make_float4(0, 0, 0, 0), wb = make_float4(0, 0, 0, 0);
        if (doC) {
            wa = ((const float4*)(W3s + (size_t)i * NH + gb))[lane];
            wb = ((const float4*)(W3s + (size_t)(NI + i) * NH + gb))[lane];
        }

        if (doB) {
            // fused load+consume: compiler software-pipelines within the
            // (256,4) 64-VGPR budget; co-resident blocks hide L2 latency.
            const uint4* pbase = PB + (size_t)(dd * 17) * 256 + (gb >> 2) + lane;
#pragma unroll
            for (int u2 = 0; u2 < 17; ++u2) {
                uint4 g = pbase[u2 * 256];
                consume_pair1(g, *(const float2*)&a1S[w][2 * u2], acc);
            }
        }

        // Phase C (fp32 W3; zeros beyond prefix keep it exact)
        float s00 = 0, s01 = 0;
        if (doC) {
            float hx = fmaxf(acc.x, 0.f), hy = fmaxf(acc.y, 0.f);
            float hz = fmaxf(acc.z, 0.f), hw = fmaxf(acc.w, 0.f);
            s00 = fmaf(wa.x, hx, fmaf(wa.y, hy, fmaf(wa.z, hz, wa.w * hw)));
            s01 = fmaf(wb.x, hx, fmaf(wb.y, hy, fmaf(wb.z, hz, wb.w * hw)));
#pragma unroll
            for (int m = 32; m >= 1; m >>= 1) {
                s00 += __shfl_xor(s00, m, 64);
                s01 += __shfl_xor(s01, m, 64);
            }
        }
        if (lane == 0)
            *((float2*)&part[i & 1][w][0]) = make_float2(s00, s01);
        __syncthreads();

        // combine — replicated in every wave; x published to own-wave xs only
        const float* pb = &part[i & 1][0][0];
        float4 q0 = ((const float4*)pb)[0], q1 = ((const float4*)pb)[1];
        float bi  = b3S[i];
        float bia = b3S[NI + i];
        float p00 = ((q0.x + q0.z) + (q1.x + q1.z)) + bi;
        float p01 = ((q0.y + q0.w) + (q1.y + q1.w)) + bia;
        float e20 = __expf(2.f * fminf(p01, 15.f));
        float ta0 = (e20 - 1.f) / (e20 + 1.f);
        float x0  = fmaf(xinS[i], __expf(ta0), p00);
        J -= ta0;
        if (lane == 0) xsS[w][i] = x0;
    }

    if (w == 0) {
        if (lane < NI) out[row * NI + lane] = xsS[0][lane];
        if (lane == 0) out[NB * NI + row] = J;
    }
}

extern "C" void kernel_launch(void* const* d_in, const int* in_sizes, int n_in,
                              void* d_out, int out_size, void* d_ws, size_t ws_size,
                              hipStream_t stream) {
    const float* inputs = (const float*)d_in[0];
    const float* W1     = (const float*)d_in[1];
    const float* b1     = (const float*)d_in[2];
    const float* W2     = (const float*)d_in[3];
    const float* b2     = (const float*)d_in[4];
    const float* W3     = (const float*)d_in[5];
    const float* b3     = (const float*)d_in[6];
    float* out = (float*)d_out;
    float* ws  = (float*)d_ws;

    prep_all<<<527, 256, 0, stream>>>(W1, b1, W2, b2, W3, ws);
    made_scan<<<NB, 256, 0, stream>>>(inputs, b3, ws, out);
}

// Round 5
// 162.593 us; speedup vs baseline: 1.3052x; 1.1281x over previous
//
#include <hip/hip_runtime.h>
#include <math.h>

#define NI   32
#define NH   1024
#define NB   1024

// ws layout. g-axis (h2) degree-SORTED; h1-axis natural. W2/W1 stored as BF16.
//   fp32: b1s[1056] @0, b2s[1024] @1056, W3s[64][1024] @2080
//   W1B  (uint)  @67616 : W1B[k][su] = bf16(W1m[j=2k][su]) | bf16(W1m[2k+1][su])<<16
//   PB   (uint4) @84512 : panel dd, pair u2, sg-quad Q, halves r=0/1
#define OFF_B1S 0
#define OFF_B2S 1056
#define OFF_W3S 2080
#define OFF_W1B 67616            // float-index (4B units)
#define OFF_PB  84512            // float-index; PB block idx = (dd*17+u2)*256 + Q

__device__ __forceinline__ int base_of(int d) { return (d == 0) ? 0 : 33 * d + 1; }

__device__ __forceinline__ unsigned short f2bf(float f) {   // RNE bf16
    unsigned u = __float_as_uint(f);
    return (unsigned short)((u + 0x7FFFu + ((u >> 16) & 1u)) >> 16);
}
__device__ __forceinline__ float bflo(unsigned u) { return __uint_as_float(u << 16); }
__device__ __forceinline__ float bfhi(unsigned u) { return __uint_as_float(u & 0xFFFF0000u); }

// ---- fast wave-wide sum: DPP for xor1/2/4/8, permlane-swap for 16/32 ----
// R18: replaces the 6-level __shfl_xor butterfly (6 dependent ds_swizzle,
// ~120cyc each = ~700cyc/step on every wave's critical path) with
// DPP adds (~2-4cyc each) + permlane16/32_swap (r0+r1 = s + s[partner]).
// Mirrors (not exact xor) are valid: values are uniform within each
// already-reduced group, so any pairing with the partner group sums right.
template <int CTRL>
__device__ __forceinline__ float dpp_add(float s) {
    int t = __builtin_amdgcn_update_dpp(0, __float_as_int(s), CTRL, 0xF, 0xF, true);
    return s + __int_as_float(t);
}

__device__ __forceinline__ float wave_allsum(float s) {
    s = dpp_add<0xB1>(s);    // quad_perm [1,0,3,2] : + s[lane^1]
    s = dpp_add<0x4E>(s);    // quad_perm [2,3,0,1] : + s[lane^2]
    s = dpp_add<0x141>(s);   // row_half_mirror     : + partner quad in 8
    s = dpp_add<0x140>(s);   // row_mirror          : + partner 8 in 16
#if __has_builtin(__builtin_amdgcn_permlane16_swap)
    {
        using uint2v = __attribute__((ext_vector_type(2))) unsigned int;
        uint2v r = __builtin_amdgcn_permlane16_swap(
            __float_as_uint(s), __float_as_uint(s), false, false);
        s = __uint_as_float(r.x) + __uint_as_float(r.y);
    }
#else
    s += __int_as_float(__builtin_amdgcn_ds_swizzle(__float_as_int(s), 0x401F));
#endif
#if __has_builtin(__builtin_amdgcn_permlane32_swap)
    {
        using uint2v = __attribute__((ext_vector_type(2))) unsigned int;
        uint2v r = __builtin_amdgcn_permlane32_swap(
            __float_as_uint(s), __float_as_uint(s), false, false);
        s = __uint_as_float(r.x) + __uint_as_float(r.y);
    }
#else
    s += __shfl_xor(s, 32, 64);
#endif
    return s;
}

// ---- prep (identical to baseline) ----
template <int CNT>
__device__ __forceinline__ void prep_w2_cls(int d, int oh0, const float* __restrict__ W2,
                                            unsigned short* __restrict__ pb16, int t,
                                            float (*tile)[65]) {
    const int bse = base_of(d);
#pragma unroll 1
    for (int e = t; e < CNT * 64; e += 256) {
        int k = e >> 6, c = e & 63;
        int og = d + 31 * k;
        tile[k][c] = W2[(size_t)og * NH + oh0 + c];
    }
    __syncthreads();
#pragma unroll 1
    for (int e = t; e < 64 * CNT; e += 256) {
        int oh_l = e / CNT;
        int k = e - oh_l * CNT;
        int oh = oh0 + oh_l;
        int dd = oh % 31, u = oh / 31;
        int sg = bse + k;
        float v = (d >= dd) ? tile[k][oh_l] : 0.0f;
        size_t a = (size_t)((dd * 17 + (u >> 1)) * 256 + (sg >> 2)) * 8
                 + (u & 1) * 4 + (sg & 3);
        pb16[a] = f2bf(v);
    }
}

template <int CNT>
__device__ __forceinline__ void prep_small_cls(int d, const float* __restrict__ W1,
        const float* __restrict__ b1, const float* __restrict__ b2,
        const float* __restrict__ W3, float* __restrict__ ws, int t) {
    const int bse = base_of(d);
    unsigned short* w1b16 = (unsigned short*)(ws + OFF_W1B);
#pragma unroll 1
    for (int e = t; e < 64 * CNT; e += 256) {
        int o = e / CNT, k = e - o * CNT;
        int og = d + 31 * k;
        float v = (((o & 31) - 1) >= d) ? W3[(size_t)o * NH + og] : 0.0f;
        ws[OFF_W3S + (size_t)o * NH + bse + k] = v;
    }
#pragma unroll 1
    for (int e = t; e < 32 * CNT; e += 256) {
        int j = e / CNT, k = e - j * CNT;
        int og = d + 31 * k;
        int su = bse + k;
        float v = (d >= j) ? W1[og * NI + j] : 0.0f;
        w1b16[(size_t)((j >> 1) * 1056 + su) * 2 + (j & 1)] = f2bf(v);
    }
    if (t < CNT) {
        int og = d + 31 * t;
        ws[OFF_B1S + bse + t] = b1[og];
        ws[OFF_B2S + bse + t] = b2[og];
    }
}

__global__ __launch_bounds__(256) void prep_all(const float* __restrict__ W1,
        const float* __restrict__ b1, const float* __restrict__ W2,
        const float* __restrict__ b2, const float* __restrict__ W3,
        float* __restrict__ ws) {
    __shared__ float tile[34][65];
    const int bid = blockIdx.x, t = threadIdx.x;
    unsigned short* pb16 = (unsigned short*)(ws + OFF_PB);
    if (bid < 496) {
        int d = bid >> 4, oh0 = (bid & 15) * 64;
        if (d == 0) prep_w2_cls<34>(0, oh0, W2, pb16, t, tile);
        else        prep_w2_cls<33>(d, oh0, W2, pb16, t, tile);
    } else {
        int d = bid - 496;
        if (d == 0) prep_small_cls<34>(0, W1, b1, b2, W3, ws, t);
        else        prep_small_cls<33>(d, W1, b1, b2, W3, ws, t);
    }
}

// consume one bf16 pair-load; coefficients from a 16B broadcast LDS read:
// av = { a0[2u2], a1[2u2], a0[2u2+1], a1[2u2+1] }
__device__ __forceinline__ void consume_pair(uint4 g, float4 av,
                                             float4& acc0, float4& acc1) {
    float f0 = bflo(g.x), f1 = bfhi(g.x), f2 = bflo(g.y), f3 = bfhi(g.y);
    float f4 = bflo(g.z), f5 = bfhi(g.z), f6 = bflo(g.w), f7 = bfhi(g.w);
    acc0.x = fmaf(av.x, f0, acc0.x); acc0.y = fmaf(av.x, f1, acc0.y);
    acc0.z = fmaf(av.x, f2, acc0.z); acc0.w = fmaf(av.x, f3, acc0.w);
    acc1.x = fmaf(av.y, f0, acc1.x); acc1.y = fmaf(av.y, f1, acc1.y);
    acc1.z = fmaf(av.y, f2, acc1.z); acc1.w = fmaf(av.y, f3, acc1.w);
    acc0.x = fmaf(av.z, f4, acc0.x); acc0.y = fmaf(av.z, f5, acc0.y);
    acc0.z = fmaf(av.z, f6, acc0.z); acc0.w = fmaf(av.z, f7, acc0.w);
    acc1.x = fmaf(av.w, f4, acc1.x); acc1.y = fmaf(av.w, f5, acc1.y);
    acc1.z = fmaf(av.w, f6, acc1.z); acc1.w = fmaf(av.w, f7, acc1.w);
}

// R18 = baseline R14 2-row structure (proven 99.6us; 2-row amortizes the
// PB/wk weight stream over 2 batch rows — the 1-row experiments R15-R17
// all lost to the doubled per-row stream cost) + wave_allsum fast reduce.
// Block = 2 batch rows x 4 slice-waves (float4/lane). 512 blocks = 2/CU.
__global__ __launch_bounds__(256, 2) void made_scan(
        const float* __restrict__ inputs,
        const float* __restrict__ b3,
        const float* __restrict__ ws,
        float* __restrict__ out) {
    __shared__ float xsS[4][2][36];     // per-wave private x (row-major, pad 36)
    __shared__ float a1S[4][36][2];     // per-wave private a1 [unit][row]
    __shared__ float part[2][4][4];
    __shared__ float b3S[64];
    __shared__ float xinS[2][NI];

    const int lane = threadIdx.x & 63;
    const int w    = threadIdx.x >> 6;
    const int pairity = ((blockIdx.x >> 8) ^ blockIdx.x) & 1;
    const int q    = w ^ (pairity * 3);
    const int gb   = q * 256;
    const int row0 = blockIdx.x * 2;

    const float* b1s = ws + OFF_B1S;
    const float* b2s = ws + OFF_B2S;
    const float* W3s = ws + OFF_W3S;
    const unsigned* W1B = (const unsigned*)(ws + OFF_W1B);
    const uint4*    PB  = (const uint4*)(ws + OFF_PB);

    float4 acc0 = ((const float4*)(b2s + gb))[lane];
    float4 acc1 = acc0;
    float J0 = 0.f, J1 = 0.f;

    // init: stage b3/xin; zero private xs
    if (w == 0) {
        b3S[lane] = b3[lane];
        if (lane < NI) {
            xinS[0][lane] = inputs[row0 * NI + lane];
            xinS[1][lane] = inputs[(row0 + 1) * NI + lane];
        }
    }
    {
        float* px = &xsS[w][0][0];
        for (int k = lane; k < 72; k += 64) px[k] = 0.f;
    }
    __syncthreads();

    // step 0: W3 rows 0/32 fully masked -> p = (b3[0], b3[32])
    {
        float p00 = b3S[0], p01 = b3S[NI];
        float e20 = __expf(2.f * fminf(p01, 15.f));
        float ta  = (e20 - 1.f) / (e20 + 1.f);
        float es  = __expf(ta);
        float x0  = fmaf(xinS[0][0], es, p00);
        float x1  = fmaf(xinS[1][0], es, p00);
        J0 -= ta; J1 -= ta;
        if (lane == 0) { xsS[w][0][0] = x0; xsS[w][1][0] = x1; }
    }

#pragma unroll 1
    for (int i = 1; i < NI; ++i) {
        const int dd   = i - 1;
        const int goff = base_of(dd);
        const int cnt  = (i == 1) ? 34 : 33;
        const bool doB = (gb + 256 > goff);
        const bool doC = (gb < 33 * i + 1);

        float4 wa = make_float4(0, 0, 0, 0), wb = make_float4(0, 0, 0, 0);
        if (doC) {
            wa = ((const float4*)(W3s + (size_t)i * NH + gb))[lane];
            wb = ((const float4*)(W3s + (size_t)(NI + i) * NH + gb))[lane];
        }

        if (doB) {
            const uint4* pbase = PB + (size_t)(dd * 17) * 256 + (gb >> 2) + lane;
            uint4 G1[9];
#pragma unroll
            for (int u2 = 0; u2 < 9; ++u2) G1[u2] = pbase[u2 * 256];
            __builtin_amdgcn_sched_barrier(0);

            // Phase A: 32 taps; x from private LDS (b128 broadcast), W1 bf16.
            // Taps j>=i have weight exactly 0 and xs[j]=0 -> exact.
            const int su = goff + lane;
            float bz = b1s[su];
            unsigned wk[16];
#pragma unroll
            for (int k = 0; k < 16; ++k) wk[k] = W1B[k * 1056 + su];
            float zA0 = bz, zA1 = 0, zA2 = 0, zA3 = 0;
            float zB0 = bz, zB1 = 0, zB2 = 0, zB3 = 0;
#pragma unroll
            for (int j4 = 0; j4 < 8; ++j4) {
                float4 xq0 = *(const float4*)&xsS[w][0][4 * j4];
                float4 xq1 = *(const float4*)&xsS[w][1][4 * j4];
                float w0 = bflo(wk[2 * j4]),     w1 = bfhi(wk[2 * j4]);
                float w2 = bflo(wk[2 * j4 + 1]), w3 = bfhi(wk[2 * j4 + 1]);
                zA0 = fmaf(xq0.x, w0, zA0); zB0 = fmaf(xq1.x, w0, zB0);
                zA1 = fmaf(xq0.y, w1, zA1); zB1 = fmaf(xq1.y, w1, zB1);
                zA2 = fmaf(xq0.z, w2, zA2); zB2 = fmaf(xq1.z, w2, zB2);
                zA3 = fmaf(xq0.w, w3, zA3); zB3 = fmaf(xq1.w, w3, zB3);
            }
            const bool ok = lane < cnt;
            float a0 = ok ? fmaxf((zA0 + zA1) + (zA2 + zA3), 0.f) : 0.f;
            float a1 = ok ? fmaxf((zB0 + zB1) + (zB2 + zB3), 0.f) : 0.f;
            if (lane < 36) {                 // publish to own-wave a1S
                float2 v = make_float2(a0, a1);
                *(float2*)&a1S[w][lane][0] = v;
            }
            __builtin_amdgcn_sched_barrier(0);

            uint4 G2[8];
#pragma unroll
            for (int u2 = 0; u2 < 8; ++u2) G2[u2] = pbase[(9 + u2) * 256];
            __builtin_amdgcn_sched_barrier(0);
#pragma unroll
            for (int u2 = 0; u2 < 9; ++u2)
                consume_pair(G1[u2], *(const float4*)&a1S[w][2 * u2][0], acc0, acc1);
            __builtin_amdgcn_sched_barrier(0);
#pragma unroll
            for (int u2 = 0; u2 < 8; ++u2)
                consume_pair(G2[u2], *(const float4*)&a1S[w][18 + 2 * u2][0], acc0, acc1);
        }

        // Phase C (fp32 W3; zeros beyond prefix keep it exact)
        float s00 = 0, s01 = 0, s10 = 0, s11 = 0;
        if (doC) {
            float hx, hy, hz, hw;
            hx = fmaxf(acc0.x, 0.f); hy = fmaxf(acc0.y, 0.f);
            hz = fmaxf(acc0.z, 0.f); hw = fmaxf(acc0.w, 0.f);
            s00 = fmaf(wa.x, hx, fmaf(wa.y, hy, fmaf(wa.z, hz, wa.w * hw)));
            s01 = fmaf(wb.x, hx, fmaf(wb.y, hy, fmaf(wb.z, hz, wb.w * hw)));
            hx = fmaxf(acc1.x, 0.f); hy = fmaxf(acc1.y, 0.f);
            hz = fmaxf(acc1.z, 0.f); hw = fmaxf(acc1.w, 0.f);
            s10 = fmaf(wa.x, hx, fmaf(wa.y, hy, fmaf(wa.z, hz, wa.w * hw)));
            s11 = fmaf(wb.x, hx, fmaf(wb.y, hy, fmaf(wb.z, hz, wb.w * hw)));
            // fast wave-wide sums (DPP + permlane swaps), replaces 6-level
            // ds_swizzle butterfly (~700cyc dependent chain -> ~40cyc)
            s00 = wave_allsum(s00); s01 = wave_allsum(s01);
            s10 = wave_allsum(s10); s11 = wave_allsum(s11);
        }
        if (lane == 0)
            *((float4*)&part[i & 1][w][0]) = make_float4(s00, s01, s10, s11);
        __syncthreads();

        // combine — replicated in every wave; x published to own-wave xs only
        const float* pb = &part[i & 1][0][0];
        float4 q0 = ((const float4*)pb)[0], q1 = ((const float4*)pb)[1];
        float4 q2 = ((const float4*)pb)[2], q3 = ((const float4*)pb)[3];
        float bi  = b3S[i];
        float bia = b3S[NI + i];
        float p00 = ((q0.x + q1.x) + (q2.x + q3.x)) + bi;
        float p01 = ((q0.y + q1.y) + (q2.y + q3.y)) + bia;
        float p10 = ((q0.z + q1.z) + (q2.z + q3.z)) + bi;
        float p11 = ((q0.w + q1.w) + (q2.w + q3.w)) + bia;
        float e20 = __expf(2.f * fminf(p01, 15.f));
        float ta0 = (e20 - 1.f) / (e20 + 1.f);
        float x0  = fmaf(xinS[0][i], __expf(ta0), p00);
        float e21 = __expf(2.f * fminf(p11, 15.f));
        float ta1 = (e21 - 1.f) / (e21 + 1.f);
        float x1  = fmaf(xinS[1][i], __expf(ta1), p10);
        J0 -= ta0; J1 -= ta1;
        if (lane == 0) { xsS[w][0][i] = x0; xsS[w][1][i] = x1; }
    }

    if (w == 0) {
        if (lane < NI) {
            out[row0 * NI + lane]       = xsS[0][0][lane];
            out[(row0 + 1) * NI + lane] = xsS[0][1][lane];
        }
        if (lane == 0) {
            out[NB * NI + row0]     = J0;
            out[NB * NI + row0 + 1] = J1;
        }
    }
}

extern "C" void kernel_launch(void* const* d_in, const int* in_sizes, int n_in,
                              void* d_out, int out_size, void* d_ws, size_t ws_size,
                              hipStream_t stream) {
    const float* inputs = (const float*)d_in[0];
    const float* W1     = (const float*)d_in[1];
    const float* b1     = (const float*)d_in[2];
    const float* W2     = (const float*)d_in[3];
    const float* b2     = (const float*)d_in[4];
    const float* W3     = (const float*)d_in[5];
    const float* b3     = (const float*)d_in[6];
    float* out = (float*)d_out;
    float* ws  = (float*)d_ws;

    prep_all<<<527, 256, 0, stream>>>(W1, b1, W2, b2, W3, ws);
    made_scan<<<NB / 2, 256, 0, stream>>>(inputs, b3, ws, out);
}

// Round 6
// 139.643 us; speedup vs baseline: 1.5197x; 1.1643x over previous
//
#include <hip/hip_runtime.h>
#include <hip/hip_fp16.h>
#include <math.h>

#define NI   32
#define NH   1024
#define NB   1024

// ws layout. g-axis (h2) degree-SORTED; h1-axis natural. W2/W1 stored as F16
// (R19: was bf16 — f16 has 10 mantissa bits vs 7, same 2B footprint, and
// enables v_dot2_f32_f16 which fuses unpack+2xFMA into one instruction).
//   fp32: b1s[1056] @0, b2s[1024] @1056, W3s[64][1024] @2080
//   W1B  (uint)  @67616 : W1B[k][su] = f16(W1m[j=2k][su]) | f16(W1m[2k+1][su])<<16
//   PB   (uint4) @84512 : panel dd, pair u2, sg-quad Q; each uint packs the
//                         (u even, u odd) k-pair for one sg unit (dot2-ready)
#define OFF_B1S 0
#define OFF_B2S 1056
#define OFF_W3S 2080
#define OFF_W1B 67616            // float-index (4B units)
#define OFF_PB  84512            // float-index; PB block idx = (dd*17+u2)*256 + Q

__device__ __forceinline__ int base_of(int d) { return (d == 0) ? 0 : 33 * d + 1; }

__device__ __forceinline__ unsigned short f2h(float f) {   // RNE f32->f16
    return __half_as_ushort(__float2half(f));
}

typedef _Float16 h2v __attribute__((ext_vector_type(2)));
__device__ __forceinline__ h2v as_h2(unsigned u) {
    union { unsigned u; h2v h; } c; c.u = u; return c.h;
}
// acc += a.h0*b.h0 + a.h1*b.h1  (exact f16 products, f32 accumulate)
__device__ __forceinline__ float fdot2u(unsigned a, unsigned b, float c) {
#if __has_builtin(__builtin_amdgcn_fdot2)
    return __builtin_amdgcn_fdot2(as_h2(a), as_h2(b), c, false);
#else
    h2v ah = as_h2(a), bh = as_h2(b);
    return fmaf((float)ah.x, (float)bh.x, fmaf((float)ah.y, (float)bh.y, c));
#endif
}

// ---- fast wave-wide sum: DPP for xor1/2/4/8, permlane-swap for 16/32 ----
// (R18 win, kept. Mirrors valid: values uniform within each reduced group.)
template <int CTRL>
__device__ __forceinline__ float dpp_add(float s) {
    int t = __builtin_amdgcn_update_dpp(0, __float_as_int(s), CTRL, 0xF, 0xF, true);
    return s + __int_as_float(t);
}

__device__ __forceinline__ float wave_allsum(float s) {
    s = dpp_add<0xB1>(s);    // quad_perm [1,0,3,2] : + s[lane^1]
    s = dpp_add<0x4E>(s);    // quad_perm [2,3,0,1] : + s[lane^2]
    s = dpp_add<0x141>(s);   // row_half_mirror     : + partner quad in 8
    s = dpp_add<0x140>(s);   // row_mirror          : + partner 8 in 16
#if __has_builtin(__builtin_amdgcn_permlane16_swap)
    {
        using uint2v = __attribute__((ext_vector_type(2))) unsigned int;
        uint2v r = __builtin_amdgcn_permlane16_swap(
            __float_as_uint(s), __float_as_uint(s), false, false);
        s = __uint_as_float(r.x) + __uint_as_float(r.y);
    }
#else
    s += __int_as_float(__builtin_amdgcn_ds_swizzle(__float_as_int(s), 0x401F));
#endif
#if __has_builtin(__builtin_amdgcn_permlane32_swap)
    {
        using uint2v = __attribute__((ext_vector_type(2))) unsigned int;
        uint2v r = __builtin_amdgcn_permlane32_swap(
            __float_as_uint(s), __float_as_uint(s), false, false);
        s = __uint_as_float(r.x) + __uint_as_float(r.y);
    }
#else
    s += __shfl_xor(s, 32, 64);
#endif
    return s;
}

// ---- prep ----
template <int CNT>
__device__ __forceinline__ void prep_w2_cls(int d, int oh0, const float* __restrict__ W2,
                                            unsigned short* __restrict__ pb16, int t,
                                            float (*tile)[65]) {
    const int bse = base_of(d);
#pragma unroll 1
    for (int e = t; e < CNT * 64; e += 256) {
        int k = e >> 6, c = e & 63;
        int og = d + 31 * k;
        tile[k][c] = W2[(size_t)og * NH + oh0 + c];
    }
    __syncthreads();
#pragma unroll 1
    for (int e = t; e < 64 * CNT; e += 256) {
        int oh_l = e / CNT;
        int k = e - oh_l * CNT;
        int oh = oh0 + oh_l;
        int dd = oh % 31, u = oh / 31;
        int sg = bse + k;
        float v = (d >= dd) ? tile[k][oh_l] : 0.0f;
        // R19 layout: halfword = (sg&3)*2 + (u&1)  -> per-unit k-pairs adjacent
        size_t a = (size_t)((dd * 17 + (u >> 1)) * 256 + (sg >> 2)) * 8
                 + (sg & 3) * 2 + (u & 1);
        pb16[a] = f2h(v);
    }
}

template <int CNT>
__device__ __forceinline__ void prep_small_cls(int d, const float* __restrict__ W1,
        const float* __restrict__ b1, const float* __restrict__ b2,
        const float* __restrict__ W3, float* __restrict__ ws, int t) {
    const int bse = base_of(d);
    unsigned short* w1b16 = (unsigned short*)(ws + OFF_W1B);
#pragma unroll 1
    for (int e = t; e < 64 * CNT; e += 256) {
        int o = e / CNT, k = e - o * CNT;
        int og = d + 31 * k;
        float v = (((o & 31) - 1) >= d) ? W3[(size_t)o * NH + og] : 0.0f;
        ws[OFF_W3S + (size_t)o * NH + bse + k] = v;
    }
#pragma unroll 1
    for (int e = t; e < 32 * CNT; e += 256) {
        int j = e / CNT, k = e - j * CNT;
        int og = d + 31 * k;
        int su = bse + k;
        float v = (d >= j) ? W1[og * NI + j] : 0.0f;
        w1b16[(size_t)((j >> 1) * 1056 + su) * 2 + (j & 1)] = f2h(v);
    }
    if (t < CNT) {
        int og = d + 31 * t;
        ws[OFF_B1S + bse + t] = b1[og];
        ws[OFF_B2S + bse + t] = b2[og];
    }
}

__global__ __launch_bounds__(256) void prep_all(const float* __restrict__ W1,
        const float* __restrict__ b1, const float* __restrict__ W2,
        const float* __restrict__ b2, const float* __restrict__ W3,
        float* __restrict__ ws) {
    __shared__ float tile[34][65];
    const int bid = blockIdx.x, t = threadIdx.x;
    unsigned short* pb16 = (unsigned short*)(ws + OFF_PB);
    if (bid < 496) {
        int d = bid >> 4, oh0 = (bid & 15) * 64;
        if (d == 0) prep_w2_cls<34>(0, oh0, W2, pb16, t, tile);
        else        prep_w2_cls<33>(d, oh0, W2, pb16, t, tile);
    } else {
        int d = bid - 496;
        if (d == 0) prep_small_cls<34>(0, W1, b1, b2, W3, ws, t);
        else        prep_small_cls<33>(d, W1, b1, b2, W3, ws, t);
    }
}

// consume one f16 pair-load with dot2: g.{x,y,z,w} = k-pair for unit sg0..3;
// av.x = packed (a0[2u2],a0[2u2+1]), av.y = same for row 1.
__device__ __forceinline__ void consume_pair(uint4 g, uint2 av,
                                             float4& acc0, float4& acc1) {
    acc0.x = fdot2u(av.x, g.x, acc0.x);
    acc0.y = fdot2u(av.x, g.y, acc0.y);
    acc0.z = fdot2u(av.x, g.z, acc0.z);
    acc0.w = fdot2u(av.x, g.w, acc0.w);
    acc1.x = fdot2u(av.y, g.x, acc1.x);
    acc1.y = fdot2u(av.y, g.y, acc1.y);
    acc1.z = fdot2u(av.y, g.z, acc1.z);
    acc1.w = fdot2u(av.y, g.w, acc1.w);
}

// R19 = R18 structure (2 rows x 4 slice-waves, 512 blocks, wave_allsum) with
// the bf16-unpack+FMA streams replaced by f16 v_dot2_f32_f16:
//   consume: 17x(8 unpack + 16 fma) = 408 VALU  ->  17x8 fdot2 = 136
//   Phase A: 32 unpack + 64 fma     =  96 VALU  ->  32 fdot2
// x taps and a coefficients published as packed f16 pairs (xsS keeps the
// exact f32 copy for the output path).
__global__ __launch_bounds__(256, 2) void made_scan(
        const float* __restrict__ inputs,
        const float* __restrict__ b3,
        const float* __restrict__ ws,
        float* __restrict__ out) {
    __shared__ float    xsS[4][2][36];  // per-wave private x, f32 (output path)
    __shared__ unsigned xsH[4][2][20];  // per-wave x as packed f16 pairs
    __shared__ unsigned a1H[4][36];     // per-wave a pairs: [u2*2]=row0, [u2*2+1]=row1
    __shared__ float part[2][4][4];
    __shared__ float b3S[64];
    __shared__ float xinS[2][NI];

    const int lane = threadIdx.x & 63;
    const int w    = threadIdx.x >> 6;
    const int pairity = ((blockIdx.x >> 8) ^ blockIdx.x) & 1;
    const int q    = w ^ (pairity * 3);
    const int gb   = q * 256;
    const int row0 = blockIdx.x * 2;

    const float* b1s = ws + OFF_B1S;
    const float* b2s = ws + OFF_B2S;
    const float* W3s = ws + OFF_W3S;
    const unsigned* W1B = (const unsigned*)(ws + OFF_W1B);
    const uint4*    PB  = (const uint4*)(ws + OFF_PB);

    float4 acc0 = ((const float4*)(b2s + gb))[lane];
    float4 acc1 = acc0;
    float J0 = 0.f, J1 = 0.f;

    // init: stage b3/xin; zero private xs (f32 and f16 copies)
    if (w == 0) {
        b3S[lane] = b3[lane];
        if (lane < NI) {
            xinS[0][lane] = inputs[row0 * NI + lane];
            xinS[1][lane] = inputs[(row0 + 1) * NI + lane];
        }
    }
    {
        float* px = &xsS[w][0][0];
        for (int k = lane; k < 72; k += 64) px[k] = 0.f;
        unsigned* ph = &xsH[w][0][0];
        for (int k = lane; k < 40; k += 64) ph[k] = 0u;
    }
    __syncthreads();

    // step 0: W3 rows 0/32 fully masked -> p = (b3[0], b3[32])
    {
        float p00 = b3S[0], p01 = b3S[NI];
        float e20 = __expf(2.f * fminf(p01, 15.f));
        float ta  = (e20 - 1.f) / (e20 + 1.f);
        float es  = __expf(ta);
        float x0  = fmaf(xinS[0][0], es, p00);
        float x1  = fmaf(xinS[1][0], es, p00);
        J0 -= ta; J1 -= ta;
        if (lane == 0) {
            xsS[w][0][0] = x0; xsS[w][1][0] = x1;
            ((unsigned short*)&xsH[w][0][0])[0] = f2h(x0);
            ((unsigned short*)&xsH[w][1][0])[0] = f2h(x1);
        }
    }

#pragma unroll 1
    for (int i = 1; i < NI; ++i) {
        const int dd   = i - 1;
        const int goff = base_of(dd);
        const int cnt  = (i == 1) ? 34 : 33;
        const bool doB = (gb + 256 > goff);
        const bool doC = (gb < 33 * i + 1);

        float4 wa = make_float4(0, 0, 0, 0), wb = make_float4(0, 0, 0, 0);
        if (doC) {
            wa = ((const float4*)(W3s + (size_t)i * NH + gb))[lane];
            wb = ((const float4*)(W3s + (size_t)(NI + i) * NH + gb))[lane];
        }

        if (doB) {
            const uint4* pbase = PB + (size_t)(dd * 17) * 256 + (gb >> 2) + lane;
            uint4 G1[9];
#pragma unroll
            for (int u2 = 0; u2 < 9; ++u2) G1[u2] = pbase[u2 * 256];
            __builtin_amdgcn_sched_barrier(0);

            // Phase A: 32 taps via 16 dot2-pairs/row; x from packed-f16 LDS.
            // Taps j>=i have weight exactly 0 and xs[j]=0 -> exact.
            const int su = goff + lane;
            float bz = b1s[su];
            unsigned wk[16];
#pragma unroll
            for (int k = 0; k < 16; ++k) wk[k] = W1B[k * 1056 + su];
            float zA0 = bz, zA1 = 0, zA2 = 0, zA3 = 0;
            float zB0 = bz, zB1 = 0, zB2 = 0, zB3 = 0;
#pragma unroll
            for (int q4 = 0; q4 < 4; ++q4) {
                uint4 xp0 = *(const uint4*)&xsH[w][0][4 * q4];
                uint4 xp1 = *(const uint4*)&xsH[w][1][4 * q4];
                zA0 = fdot2u(xp0.x, wk[4 * q4 + 0], zA0);
                zB0 = fdot2u(xp1.x, wk[4 * q4 + 0], zB0);
                zA1 = fdot2u(xp0.y, wk[4 * q4 + 1], zA1);
                zB1 = fdot2u(xp1.y, wk[4 * q4 + 1], zB1);
                zA2 = fdot2u(xp0.z, wk[4 * q4 + 2], zA2);
                zB2 = fdot2u(xp1.z, wk[4 * q4 + 2], zB2);
                zA3 = fdot2u(xp0.w, wk[4 * q4 + 3], zA3);
                zB3 = fdot2u(xp1.w, wk[4 * q4 + 3], zB3);
            }
            const bool ok = lane < cnt;
            float a0 = ok ? fmaxf((zA0 + zA1) + (zA2 + zA3), 0.f) : 0.f;
            float a1 = ok ? fmaxf((zB0 + zB1) + (zB2 + zB3), 0.f) : 0.f;
            if (lane < 36) {                 // publish packed f16 pairs
                unsigned short* ah = (unsigned short*)&a1H[w][0];
                int u2 = lane >> 1, h = lane & 1;
                ah[u2 * 4 + h]     = f2h(a0);
                ah[u2 * 4 + 2 + h] = f2h(a1);
            }
            __builtin_amdgcn_sched_barrier(0);

            uint4 G2[8];
#pragma unroll
            for (int u2 = 0; u2 < 8; ++u2) G2[u2] = pbase[(9 + u2) * 256];
            __builtin_amdgcn_sched_barrier(0);
#pragma unroll
            for (int u2 = 0; u2 < 9; ++u2)
                consume_pair(G1[u2], *(const uint2*)&a1H[w][2 * u2], acc0, acc1);
            __builtin_amdgcn_sched_barrier(0);
#pragma unroll
            for (int u2 = 0; u2 < 8; ++u2)
                consume_pair(G2[u2], *(const uint2*)&a1H[w][18 + 2 * u2], acc0, acc1);
        }

        // Phase C (fp32 W3; zeros beyond prefix keep it exact)
        float s00 = 0, s01 = 0, s10 = 0, s11 = 0;
        if (doC) {
            float hx, hy, hz, hw;
            hx = fmaxf(acc0.x, 0.f); hy = fmaxf(acc0.y, 0.f);
            hz = fmaxf(acc0.z, 0.f); hw = fmaxf(acc0.w, 0.f);
            s00 = fmaf(wa.x, hx, fmaf(wa.y, hy, fmaf(wa.z, hz, wa.w * hw)));
            s01 = fmaf(wb.x, hx, fmaf(wb.y, hy, fmaf(wb.z, hz, wb.w * hw)));
            hx = fmaxf(acc1.x, 0.f); hy = fmaxf(acc1.y, 0.f);
            hz = fmaxf(acc1.z, 0.f); hw = fmaxf(acc1.w, 0.f);
            s10 = fmaf(wa.x, hx, fmaf(wa.y, hy, fmaf(wa.z, hz, wa.w * hw)));
            s11 = fmaf(wb.x, hx, fmaf(wb.y, hy, fmaf(wb.z, hz, wb.w * hw)));
            s00 = wave_allsum(s00); s01 = wave_allsum(s01);
            s10 = wave_allsum(s10); s11 = wave_allsum(s11);
        }
        if (lane == 0)
            *((float4*)&part[i & 1][w][0]) = make_float4(s00, s01, s10, s11);
        __syncthreads();

        // combine — replicated in every wave; x published to own-wave xs only
        const float* pb = &part[i & 1][0][0];
        float4 q0 = ((const float4*)pb)[0], q1 = ((const float4*)pb)[1];
        float4 q2 = ((const float4*)pb)[2], q3 = ((const float4*)pb)[3];
        float bi  = b3S[i];
        float bia = b3S[NI + i];
        float p00 = ((q0.x + q1.x) + (q2.x + q3.x)) + bi;
        float p01 = ((q0.y + q1.y) + (q2.y + q3.y)) + bia;
        float p10 = ((q0.z + q1.z) + (q2.z + q3.z)) + bi;
        float p11 = ((q0.w + q1.w) + (q2.w + q3.w)) + bia;
        float e20 = __expf(2.f * fminf(p01, 15.f));
        float ta0 = (e20 - 1.f) / (e20 + 1.f);
        float x0  = fmaf(xinS[0][i], __expf(ta0), p00);
        float e21 = __expf(2.f * fminf(p11, 15.f));
        float ta1 = (e21 - 1.f) / (e21 + 1.f);
        float x1  = fmaf(xinS[1][i], __expf(ta1), p10);
        J0 -= ta0; J1 -= ta1;
        if (lane == 0) {
            xsS[w][0][i] = x0; xsS[w][1][i] = x1;
            ((unsigned short*)&xsH[w][0][0])[i] = f2h(x0);
            ((unsigned short*)&xsH[w][1][0])[i] = f2h(x1);
        }
    }

    if (w == 0) {
        if (lane < NI) {
            out[row0 * NI + lane]       = xsS[0][0][lane];
            out[(row0 + 1) * NI + lane] = xsS[0][1][lane];
        }
        if (lane == 0) {
            out[NB * NI + row0]     = J0;
            out[NB * NI + row0 + 1] = J1;
        }
    }
}

extern "C" void kernel_launch(void* const* d_in, const int* in_sizes, int n_in,
                              void* d_out, int out_size, void* d_ws, size_t ws_size,
                              hipStream_t stream) {
    const float* inputs = (const float*)d_in[0];
    const float* W1     = (const float*)d_in[1];
    const float* b1     = (const float*)d_in[2];
    const float* W2     = (const float*)d_in[3];
    const float* b2     = (const float*)d_in[4];
    const float* W3     = (const float*)d_in[5];
    const float* b3     = (const float*)d_in[6];
    float* out = (float*)d_out;
    float* ws  = (float*)d_ws;

    prep_all<<<527, 256, 0, stream>>>(W1, b1, W2, b2, W3, ws);
    made_scan<<<NB / 2, 256, 0, stream>>>(inputs, b3, ws, out);
}